// Round 4
// baseline (421.460 us; speedup 1.0000x reference)
//
#include <hip/hip_runtime.h>
#include <hip/hip_fp16.h>
#include <string.h>

// mean_aggregator: out[b,:] = mean_s emb[neighbors[b,s], :]
// B=50000, S=32, N=500000, D=128. fp32 in/out.
//
// R4: two-pass fp16 (R3) with a restructured gather to discriminate between
// the two ceiling models consistent with R1-R3 data:
//   (a) fabric-BW w/ granule efficiency  -> this round is neutral (~169 us)
//   (b) per-CU outstanding VMEM-INSTRUCTION budget -> lines-in-flight scale
//       with lines/instr; this gather packs 16 lines/instr (4 rows x 256B
//       per global_load_dwordx4) vs 4 in R3 and 8 in the fp32 R2 kernel
//       -> gather ~55-70 us, total ~120-135 us.
// Layout: wave64 handles 4 rows; lane group of 16 owns one row (16 x 16B =
// 256B fp16 row). Neighbor indices via scalar path + 3 v_cndmask row-select.
// Stores: wave writes 4 adjacent rows = 2KB contiguous, fully coalesced.

#define AGG_BATCH 50000
#define AGG_S 32
#define AGG_NODES 500000
#define AGG_D 128
#define AGG_ELEMS ((size_t)AGG_NODES * AGG_D)   // 64M
#define AGG_WS_BYTES (AGG_ELEMS * 2)            // 128 MB fp16 table

// ---- Pass 1: fp32 -> fp16 table (8 elems/thread), streaming ----
__global__ __launch_bounds__(256) void agg_convert_kernel(
    const float4* __restrict__ in, uint4* __restrict__ out16) {
  const size_t i = (size_t)blockIdx.x * 256 + threadIdx.x;  // 8 floats each
  const float4 a = in[2 * i];
  const float4 b = in[2 * i + 1];
  const __half2 h0 = __floats2half2_rn(a.x, a.y);
  const __half2 h1 = __floats2half2_rn(a.z, a.w);
  const __half2 h2 = __floats2half2_rn(b.x, b.y);
  const __half2 h3 = __floats2half2_rn(b.z, b.w);
  uint4 o;
  memcpy(&o.x, &h0, 4);
  memcpy(&o.y, &h1, 4);
  memcpy(&o.z, &h2, 4);
  memcpy(&o.w, &h3, 4);
  out16[i] = o;
}

// ---- Pass 2: gather-mean, 4 rows per wave, 16B fp16 per lane ----
__global__ __launch_bounds__(256) void mean_aggregator_49795850830175_kernel(
    const int* __restrict__ neighbors,
    const unsigned char* __restrict__ tab16,   // fp16 table, row = 256B
    float* __restrict__ out) {
  const int lane = threadIdx.x & 63;
  const int wave = threadIdx.x >> 6;
  const int row_base = (blockIdx.x * 4 + wave) * 4;   // 4 rows per wave
  const int rsel = lane >> 4;                          // which row (0..3)
  const int lsub = lane & 15;                          // 16 lanes per row

  // 4 rows' neighbor lists are contiguous: nb[r*32 + s]
  const int* __restrict__ nb = neighbors + (size_t)row_base * AGG_S;

  float acc[8];
#pragma unroll
  for (int j = 0; j < 8; ++j) acc[j] = 0.f;

  const int byte_off = lsub * 16;
#pragma unroll
  for (int s = 0; s < AGG_S; ++s) {
    // scalar loads (wave-uniform)
    const int i0 = __builtin_amdgcn_readfirstlane(nb[0 * AGG_S + s]);
    const int i1 = __builtin_amdgcn_readfirstlane(nb[1 * AGG_S + s]);
    const int i2 = __builtin_amdgcn_readfirstlane(nb[2 * AGG_S + s]);
    const int i3 = __builtin_amdgcn_readfirstlane(nb[3 * AGG_S + s]);
    // per-lane row select (3 cndmask)
    const int idx = (rsel & 2) ? ((rsel & 1) ? i3 : i2)
                               : ((rsel & 1) ? i1 : i0);
    const uint4 v = *(const uint4*)(tab16 + ((size_t)idx << 8) + byte_off);
    __half2 h[4];
    memcpy(h, &v, 16);
#pragma unroll
    for (int j = 0; j < 4; ++j) {
      const float2 f = __half22float2(h[j]);
      acc[2 * j] += f.x;
      acc[2 * j + 1] += f.y;
    }
  }

  const float inv = 1.0f / (float)AGG_S;
  float4 o0 = make_float4(acc[0] * inv, acc[1] * inv, acc[2] * inv, acc[3] * inv);
  float4 o1 = make_float4(acc[4] * inv, acc[5] * inv, acc[6] * inv, acc[7] * inv);
  // lane writes 32B of row (row_base + rsel): wave covers 2KB contiguous
  float4* op = (float4*)(out + (size_t)(row_base + rsel) * AGG_D + lsub * 8);
  op[0] = o0;
  op[1] = o1;
}

// ---- Fallback: direct fp32 gather (R2 kernel) if ws too small ----
__global__ __launch_bounds__(256) void agg_direct_kernel(
    const int* __restrict__ neighbors,
    const float2* __restrict__ emb,
    float2* __restrict__ out) {
  const int lane = threadIdx.x & 63;
  int row = blockIdx.x * 4 + (threadIdx.x >> 6);
  row = __builtin_amdgcn_readfirstlane(row);
  const int* __restrict__ nb = neighbors + (size_t)row * AGG_S;
  float ax = 0.f, ay = 0.f;
#pragma unroll
  for (int s = 0; s < AGG_S; ++s) {
    const int idx = __builtin_amdgcn_readfirstlane(nb[s]);
    const float2 v = emb[(size_t)idx * (AGG_D / 2) + lane];
    ax += v.x;
    ay += v.y;
  }
  const float inv = 1.0f / (float)AGG_S;
  out[(size_t)row * (AGG_D / 2) + lane] = make_float2(ax * inv, ay * inv);
}

extern "C" void kernel_launch(void* const* d_in, const int* in_sizes, int n_in,
                              void* d_out, int out_size, void* d_ws, size_t ws_size,
                              hipStream_t stream) {
  const int* neighbors = (const int*)d_in[0];   // [B, S] int32
  const float* emb = (const float*)d_in[1];     // [N, D] fp32

  if (ws_size >= AGG_WS_BYTES) {
    const int conv_grid = (int)(AGG_ELEMS / 8 / 256);  // 31250
    agg_convert_kernel<<<conv_grid, 256, 0, stream>>>(
        (const float4*)emb, (uint4*)d_ws);
    // 16 rows per block (4 waves x 4 rows), 50000/16 = 3125
    mean_aggregator_49795850830175_kernel<<<AGG_BATCH / 16, 256, 0, stream>>>(
        neighbors, (const unsigned char*)d_ws, (float*)d_out);
  } else {
    agg_direct_kernel<<<AGG_BATCH / 4, 256, 0, stream>>>(
        neighbors, (const float2*)emb, (float2*)d_out);
  }
}